// Round 1
// baseline (9643.082 us; speedup 1.0000x reference)
//
#include <hip/hip_runtime.h>
#include <hip/hip_cooperative_groups.h>
#include <stdint.h>
#include <math.h>

namespace cg = cooperative_groups;

#define B 4
#define N 100000
#define C 128
#define F 256
#define ITERS 25
#define TOPK 15
#define NEGV -1e30f
#define TPB 256
#define NBLK ((N + TPB - 1) / TPB)   // 391
#define GRID 512                     // 2 blocks/CU co-resident (launch_bounds(256,2))

// monotone float->uint (order-preserving)
__device__ __forceinline__ uint32_t f2u(float f) {
    uint32_t u = __float_as_uint(f);
    return (u & 0x80000000u) ? ~u : (u | 0x80000000u);
}
__device__ __forceinline__ float u2f(uint32_t u) {
    uint32_t bits = (u & 0x80000000u) ? (u & 0x7FFFFFFFu) : ~u;
    return __uint_as_float(bits);
}

// bit-exact emulation of numpy f32: 2.0*(p@c.T) - |p|^2 - |c|^2
__device__ __forceinline__ float sim_np(float x, float y, float z, float an,
                                        float c0, float c1, float c2, float cn) {
    float dot = __fmaf_rn(z, c2, __fmaf_rn(y, c1, __fmul_rn(x, c0)));
    float t = __fmul_rn(2.0f, dot);   // exact
    t = __fsub_rn(t, an);
    return __fsub_rn(t, cn);
}
__device__ __forceinline__ float norm3_np(float x, float y, float z) {
    return __fadd_rn(__fadd_rn(__fmul_rn(x, x), __fmul_rn(y, y)), __fmul_rn(z, z));
}

__global__ void k_copyf(const float* __restrict__ src, float* __restrict__ dst, int n) {
    int i = blockIdx.x * blockDim.x + threadIdx.x;
    if (i < n) dst[i] = src[i];
}

// ---------------------------------------------------------------------------
// Persistent cooperative kernel: all 25 k-means iterations in one dispatch.
// Per iteration: PHASE A (assign + stable ranks + tile hist) -> grid.sync ->
// PHASE B (per-(b,c) tile-hist exclusive scan + counts) -> grid.sync ->
// PHASE C (ordered scatter into member lists) -> grid.sync ->
// PHASE D (sequential bit-exact per-cluster sums -> new centroids) -> grid.sync
// All FP ops are in the identical order as the 103-dispatch version.
// ---------------------------------------------------------------------------
__global__ __launch_bounds__(TPB, 2) void k_fused(
        const float* __restrict__ pts, const float* __restrict__ ct0,
        float* centA, float* centB,
        unsigned char* __restrict__ cl8, unsigned char* __restrict__ rank8,
        unsigned int* __restrict__ tilehist, unsigned int* __restrict__ cnt,
        unsigned int* __restrict__ clusterbase, unsigned int* __restrict__ ml) {
    cg::grid_group grid = cg::this_grid();
    const int tid = threadIdx.x;
    const int bid = blockIdx.x;
    const int lane = tid & 63;
    const int wid = tid >> 6;

    __shared__ float4 scn[C];                 // (c0,c1,c2,|c|^2)
    __shared__ unsigned int wavecnt[4][C];    // per-wave per-cluster counts
    __shared__ unsigned int sscan[2 * TPB];   // scan scratch (512)

    for (int t = 0; t < ITERS; ++t) {
        const float* cur = (t == 0) ? ct0 : ((t & 1) ? centA : centB);
        float* nxt = (t & 1) ? centB : centA;

        // ---------------- PHASE A: assignment ----------------
        for (int tile = bid; tile < B * NBLK; tile += GRID) {
            const int b = tile / NBLK;
            const int blk = tile % NBLK;
            if (tid < C) {
                float c0 = cur[(b * C + tid) * 3 + 0];
                float c1 = cur[(b * C + tid) * 3 + 1];
                float c2 = cur[(b * C + tid) * 3 + 2];
                scn[tid] = make_float4(c0, c1, c2, norm3_np(c0, c1, c2));
            }
            for (int i = tid; i < 4 * C; i += TPB) ((unsigned int*)wavecnt)[i] = 0u;
            __syncthreads();

            const int p = blk * TPB + tid;
            const bool valid = (p < N);
            int bi = 0;
            if (valid) {
                const float* pp = pts + ((size_t)b * N + (size_t)p) * 3;
                float x = pp[0], y = pp[1], z = pp[2];
                float an = norm3_np(x, y, z);
                float best = -INFINITY;
                #pragma unroll 4
                for (int c = 0; c < C; ++c) {
                    float4 cc = scn[c];
                    float s = sim_np(x, y, z, an, cc.x, cc.y, cc.z, cc.w);
                    if (s > best) { best = s; bi = c; }   // strict > = np.argmax first-max
                }
            }
            // stable (index-ordered) rank via bit-ballots — bit-identical to the
            // old O(tid) shared-memory scan, just O(7) ballots instead.
            unsigned long long same = ~0ull;
            #pragma unroll
            for (int bit = 0; bit < 7; ++bit) {
                unsigned long long bb = __ballot((bi >> bit) & 1);
                same &= ((bi >> bit) & 1) ? bb : ~bb;
            }
            unsigned long long vmask = __ballot(valid);
            same &= vmask;
            unsigned long long lt = (lane == 0) ? 0ull : (~0ull >> (64 - lane));
            int rin = (int)__popcll(same & lt);
            if (valid) {
                int leader = (int)__builtin_ctzll(same);   // same != 0 (own bit set)
                if (lane == leader) wavecnt[wid][bi] = (unsigned int)__popcll(same);
            }
            __syncthreads();
            if (valid) {
                int r = rin;
                #pragma unroll
                for (int w = 0; w < 4; ++w) if (w < wid) r += wavecnt[w][bi];
                cl8[(size_t)b * N + p] = (unsigned char)bi;
                rank8[(size_t)b * N + p] = (unsigned char)r;
            }
            if (tid < C) {
                unsigned int h = wavecnt[0][tid] + wavecnt[1][tid]
                               + wavecnt[2][tid] + wavecnt[3][tid];
                tilehist[((size_t)(b * NBLK + blk)) * C + tid] = h;
            }
            __syncthreads();
        }
        grid.sync();

        // -------- PHASE B: exclusive scan of tile hists per (b,c) chain --------
        // 512 chains, 512 blocks -> exactly one chain per block.
        for (int chain = bid; chain < B * C; chain += GRID) {
            const int b = chain / C;
            const int c = chain % C;
            unsigned int* th = tilehist + (size_t)b * NBLK * C + c;
            sscan[tid]       = (tid < NBLK)       ? th[(size_t)tid * C]         : 0u;
            sscan[tid + TPB] = (tid + TPB < NBLK) ? th[(size_t)(tid + TPB) * C] : 0u;
            __syncthreads();
            for (int off = 1; off < 2 * TPB; off <<= 1) {   // inclusive Hillis-Steele
                unsigned int a0 = sscan[tid], a1 = sscan[tid + TPB];
                unsigned int b0 = (tid >= off) ? sscan[tid - off] : 0u;
                unsigned int b1 = (tid + TPB >= off) ? sscan[tid + TPB - off] : 0u;
                __syncthreads();
                sscan[tid] = a0 + b0; sscan[tid + TPB] = a1 + b1;
                __syncthreads();
            }
            if (tid < NBLK)       th[(size_t)tid * C]         = (tid == 0) ? 0u : sscan[tid - 1];
            if (tid + TPB < NBLK) th[(size_t)(tid + TPB) * C] = sscan[tid + TPB - 1];
            if (tid == 0) cnt[b * C + c] = sscan[NBLK - 1];
            __syncthreads();
        }
        grid.sync();

        // ---------------- PHASE C: ordered scatter ----------------
        for (int tile = bid; tile < B * NBLK; tile += GRID) {
            const int b = tile / NBLK;
            const int blk = tile % NBLK;
            if (tid < C) sscan[tid] = cnt[b * C + tid];
            __syncthreads();
            for (int off = 1; off < C; off <<= 1) {          // inclusive scan over 128
                unsigned int a = 0, bb = 0;
                if (tid < C) { a = sscan[tid]; bb = (tid >= off) ? sscan[tid - off] : 0u; }
                __syncthreads();
                if (tid < C) sscan[tid] = a + bb;
                __syncthreads();
            }
            const int p = blk * TPB + tid;
            if (p < N) {
                int c = cl8[(size_t)b * N + p];
                unsigned int cb = (c == 0) ? 0u : sscan[c - 1];
                unsigned int pos = cb
                                 + tilehist[((size_t)(b * NBLK + blk)) * C + c]
                                 + (unsigned int)rank8[(size_t)b * N + p];
                ml[(size_t)b * N + pos] = (unsigned int)p;
            }
            __syncthreads();
        }
        grid.sync();

        // ---------------- PHASE D: bit-exact sequential segment sums ----------------
        {
            const int id = bid * TPB + tid;      // blocks 0..5 cover 1536 chains
            if (id < B * C * 3) {
                const int b = id / (C * 3);
                const int rem = id % (C * 3);
                const int c = rem / 3;
                const int j = rem % 3;
                unsigned int base = 0;
                for (int k = 0; k < c; ++k) base += cnt[b * C + k];
                if (j == 0) clusterbase[b * C + c] = base;   // persists for k_topk (final iter)
                const unsigned int n = cnt[b * C + c];
                const unsigned int* list = ml + (size_t)b * N + base;
                const float* P = pts + (size_t)b * N * 3;
                float s = 0.f;
                unsigned int i = 0;
                for (; i + 32 <= n; i += 32) {
                    unsigned int pidx[32];
                    #pragma unroll
                    for (int u = 0; u < 32; ++u) pidx[u] = list[i + u];
                    float tv[32];
                    #pragma unroll
                    for (int u = 0; u < 32; ++u) tv[u] = P[pidx[u] * 3 + j];
                    #pragma unroll
                    for (int u = 0; u < 32; ++u) s = __fadd_rn(s, tv[u]);   // strict np order
                }
                for (; i < n; ++i) s = __fadd_rn(s, P[list[i] * 3 + j]);
                float denom = __fadd_rn((float)n, 1e-8f);
                nxt[(b * C + c) * 3 + j] = __fdiv_rn(s, denom);
            }
        }
        grid.sync();
    }
}

// per-cluster top-15 over MEMBERS ONLY (sims computed inline vs final centroids),
// stable tie-break (smaller index), f32 softmax weights  — unchanged, proven.
__global__ __launch_bounds__(TPB) void k_topk(const unsigned int* __restrict__ ml,
        const unsigned int* __restrict__ clusterbase, const unsigned int* __restrict__ cnt,
        const float* __restrict__ pts, const float* __restrict__ cent,
        int* __restrict__ tk_idx, float* __restrict__ tk_w) {
    const int b = blockIdx.y;
    const int c = blockIdx.x;
    const int tid = threadIdx.x;
    const unsigned int base = clusterbase[b * C + c];
    const unsigned int n = cnt[b * C + c];
    const unsigned int* list = ml + (size_t)b * N + base;
    const float* P = pts + (size_t)b * N * 3;

    const float c0 = cent[(b * C + c) * 3 + 0];
    const float c1 = cent[(b * C + c) * 3 + 1];
    const float c2 = cent[(b * C + c) * 3 + 2];
    const float cnorm = norm3_np(c0, c1, c2);

    unsigned long long a[TOPK];
    #pragma unroll
    for (int i = 0; i < TOPK; ++i) a[i] = 0ull;

    for (unsigned int i = tid; i < n; i += TPB) {
        unsigned int p = list[i];
        float x = P[p * 3 + 0], y = P[p * 3 + 1], z = P[p * 3 + 2];
        float an = norm3_np(x, y, z);
        float s = sim_np(x, y, z, an, c0, c1, c2, cnorm);
        unsigned long long key = ((unsigned long long)f2u(s) << 32) | (uint32_t)(~p);
        if (key > a[0]) {
            a[0] = key;
            #pragma unroll
            for (int j = 0; j < TOPK - 1; ++j) {
                if (a[j] > a[j + 1]) {
                    unsigned long long t = a[j]; a[j] = a[j + 1]; a[j + 1] = t;
                }
            }
        }
    }

    __shared__ unsigned long long wred[4];
    __shared__ unsigned long long sel;
    __shared__ unsigned long long res[TOPK];
    const int lane = tid & 63;
    const int wid = tid >> 6;

    for (int r = 0; r < TOPK; ++r) {
        unsigned long long m = a[TOPK - 1];
        #pragma unroll
        for (int off = 32; off >= 1; off >>= 1) {
            unsigned long long o = __shfl_xor(m, off, 64);
            if (o > m) m = o;
        }
        if (lane == 0) wred[wid] = m;
        __syncthreads();
        if (tid == 0) {
            unsigned long long g = wred[0];
            #pragma unroll
            for (int w = 1; w < 4; ++w) if (wred[w] > g) g = wred[w];
            sel = g;
            res[r] = g;
        }
        __syncthreads();
        if (sel != 0ull && a[TOPK - 1] == sel) {
            #pragma unroll
            for (int j = TOPK - 1; j > 0; --j) a[j] = a[j - 1];
            a[0] = 0ull;
        }
    }

    if (tid == 0) {
        float s_[TOPK]; int id_[TOPK];
        for (int i = 0; i < TOPK; ++i) {
            unsigned long long g = res[i];
            if (g == 0ull) { s_[i] = NEGV; id_[i] = 0; }
            else { s_[i] = u2f((uint32_t)(g >> 32)); id_[i] = (int)(~(uint32_t)g); }
        }
        float smax = (s_[0] > 0.5f * NEGV) ? s_[0] : NEGV;
        float w[TOPK]; float sum = 0.f;
        for (int i = 0; i < TOPK; ++i) {
            bool valid = s_[i] > 0.5f * NEGV;
            w[i] = valid ? expf(__fsub_rn(s_[i], smax)) : 0.f;
            sum = __fadd_rn(sum, w[i]);
        }
        float den = fmaxf(sum, 1e-30f);
        for (int i = 0; i < TOPK; ++i) {
            tk_idx[((size_t)b * C + c) * TOPK + i] = id_[i];
            tk_w [((size_t)b * C + c) * TOPK + i] = __fdiv_rn(w[i], den);
        }
    }
}

// cluster_features[b][f][c] = sum_k w * ft[b][f][idx]  — unchanged, proven.
__global__ __launch_bounds__(128) void k_feat(const float* __restrict__ ft,
        const int* __restrict__ tk_idx, const float* __restrict__ tk_w,
        float* __restrict__ out_cf) {
    const int b = blockIdx.y;
    const int f = blockIdx.x;
    const int c = threadIdx.x;
    __shared__ int sid[C * TOPK];
    __shared__ float sw[C * TOPK];
    for (int i = c; i < C * TOPK; i += 128) {
        sid[i] = tk_idx[(size_t)b * C * TOPK + i];
        sw[i]  = tk_w [(size_t)b * C * TOPK + i];
    }
    __syncthreads();
    const float* row = ft + (size_t)b * F * N + (size_t)f * N;
    float acc = 0.f;
    #pragma unroll
    for (int k = 0; k < TOPK; ++k) {
        acc = __fmaf_rn(sw[c * TOPK + k], row[sid[c * TOPK + k]], acc);
    }
    out_cf[((size_t)b * F + f) * C + c] = acc;
}

extern "C" void kernel_launch(void* const* d_in, const int* in_sizes, int n_in,
                              void* d_out, int out_size, void* d_ws, size_t ws_size,
                              hipStream_t stream) {
    (void)in_sizes; (void)n_in; (void)out_size; (void)ws_size;
    const float* pts = (const float*)d_in[0];   // (B,N,3)
    const float* ft  = (const float*)d_in[1];   // (B,F,N)
    const float* ct0 = (const float*)d_in[2];   // (B,C,3)
    float* out = (float*)d_out;                 // [B*C*3 | B*F*C]

    float* ws = (float*)d_ws;
    float* centA = ws;                                   // B*C*3
    float* centB = centA + B * C * 3;                    // B*C*3
    float* tk_w = centB + B * C * 3;                     // B*C*TOPK
    int* tk_idx = (int*)(tk_w + B * C * TOPK);           // B*C*TOPK
    unsigned int* cnt = (unsigned int*)(tk_idx + B * C * TOPK);     // B*C
    unsigned int* clusterbase = cnt + B * C;                        // B*C
    unsigned int* ml = clusterbase + B * C;                         // B*N
    unsigned int* tilehist = ml + (size_t)B * N;                    // B*NBLK*C (scan in-place)
    unsigned char* cl8 = (unsigned char*)(tilehist + (size_t)B * NBLK * C);  // B*N bytes
    unsigned char* rank8 = cl8 + (size_t)B * N;                              // B*N bytes

    void* args[] = { (void*)&pts, (void*)&ct0, (void*)&centA, (void*)&centB,
                     (void*)&cl8, (void*)&rank8, (void*)&tilehist, (void*)&cnt,
                     (void*)&clusterbase, (void*)&ml };
    hipLaunchCooperativeKernel((void*)k_fused, dim3(GRID), dim3(TPB), args, 0, stream);

    // centA holds centroids after 25 updates (t=24 writes centA);
    // ml/cnt/clusterbase = partition by the t=24 assignment (matches reference).
    k_topk<<<dim3(C, B), dim3(TPB), 0, stream>>>(ml, clusterbase, cnt, pts, centA, tk_idx, tk_w);
    k_feat<<<dim3(F, B), dim3(128), 0, stream>>>(ft, tk_idx, tk_w, out + B * C * 3);
    k_copyf<<<dim3((B * C * 3 + 255) / 256), dim3(256), 0, stream>>>(centA, out, B * C * 3);
}